// Round 14
// baseline (135.920 us; speedup 1.0000x reference)
//
#include <hip/hip_runtime.h>
#include <stdint.h>

// LinearAttention: x[2,8192,1024] -> qkv proj -> per-head softmaxes ->
// context = softmax_n(k)^T v -> out = softmax_d(q) @ ctx -> @ W_out + b.
//
// R14 GEMM: 128x128 tile, BK=32, TRIPLE-buffered LDS (3x16KB=48KB) ->
// 3 blocks/CU; counted vmcnt(4) (2-deep prefetch, never drain-0 in loop);
// ONE barrier per K-tile (constraints re-derived: lgkm0 before BAR covers
// cur-buf reads vs +3-overwrite; vmcnt(4)+BAR covers next-buf residency).
// LDS swizzle for 64B rows: chunk = qq ^ ((fr>>1)&3) -> 2-way (free).
// Rest = R13: ctx fused into GEMM1 (MFMA epilogue, f16 partials), fused
// softmax(q), out = softq @ (ctx@W_out) via per-batch CW^T.

typedef _Float16 half4 __attribute__((ext_vector_type(4)));
typedef _Float16 half8 __attribute__((ext_vector_type(8)));
typedef float f32x4 __attribute__((ext_vector_type(4)));

// ---- workspace byte offsets ----
#define WS_XB 0UL             // x as f16           [16384][1024]   33.55MB
#define WS_WQKVT 33554432UL   // W_qkv^T f16        [1536][1024]     3.15MB
#define WS_CWT 37748736UL     // CW^T f16           [2][1024][512]   2.10MB
#define WS_CTXPART 54525952UL // ctx partials f16   [16][64][4096]   8.39MB
#define WS_COLPART 71303168UL // colsum partials f32[16][64][64]     0.26MB
#define WS_SQ 88080384UL      // softmax(q) f16     [16384][512]    16.78MB

__device__ __forceinline__ void gld16(const void* g, void* l) {
  // async global->LDS, 16B per lane; LDS dest = wave-uniform base + lane*16
  __builtin_amdgcn_global_load_lds(
      (const __attribute__((address_space(1))) unsigned int*)g,
      (__attribute__((address_space(3))) unsigned int*)l, 16, 0, 0);
}

// Fused prep: cvt x (f32->f16) + LDS-tiled transpose+cvt of W_qkv.
__global__ void prep_kernel(const float* __restrict__ x,
                            const float* __restrict__ Wqkv,
                            _Float16* __restrict__ xb,
                            _Float16* __restrict__ wqkvT) {
  const int blk = blockIdx.x;
  const int t = threadIdx.x;
  if (blk < 16384) {
    int i = blk * 256 + t;  // 4 f32 per thread
    f32x4 v = *(const f32x4*)(x + (size_t)i * 4);
    half4 h = {(_Float16)v[0], (_Float16)v[1], (_Float16)v[2], (_Float16)v[3]};
    *(half4*)(xb + (size_t)i * 4) = h;
  } else {
    __shared__ float sT[64 * 65];  // transposed tile, pad 65 vs bank conflicts
    const int tb = blk - 16384;
    const int r0 = (tb & 15) * 64, c0 = (tb >> 4) * 64;  // W rows / cols
    const int lr = t >> 4, lc4 = (t & 15) * 4;
#pragma unroll
    for (int s = 0; s < 4; ++s) {
      const int row = s * 16 + lr;  // coalesced: lanes sweep consecutive cols
      f32x4 v = *(const f32x4*)&Wqkv[(size_t)(r0 + row) * 1536 + c0 + lc4];
#pragma unroll
      for (int j = 0; j < 4; ++j) sT[(lc4 + j) * 65 + row] = v[j];
    }
    __syncthreads();
#pragma unroll
    for (int s = 0; s < 4; ++s) {
      const int cl = s * 16 + lr;  // output row (W col), lanes sweep W rows
      half4 o = {(_Float16)sT[cl * 65 + lc4], (_Float16)sT[cl * 65 + lc4 + 1],
                 (_Float16)sT[cl * 65 + lc4 + 2],
                 (_Float16)sT[cl * 65 + lc4 + 3]};
      *(half4*)&wqkvT[(size_t)(c0 + cl) * 1024 + r0 + lc4] = o;
    }
  }
}

// ---------------- 128x128 BK=32 triple-buffered GEMM ----------------
// A[M][K] f16 row-major, BT[N][K] f16 row-major. 256 threads = 4 waves (2Mx2N),
// per-wave output 64x64 (acc[4][4]); one MFMA per (mi,ni) per K-tile (K=32).
// LDS: 3 bufs x (A 8KB + B 8KB) = 48KB. Tile layout [128 rows][64B];
// physical chunk = logical_chunk ^ ((row>>1)&3) (16B chunks) -> 2-way banks.
// Staged linearly via global_load_lds with inverse-swizzled source chunk.

// stage a 128-row x 32-f16 tile = 2 sweeps x 1 gld16/thread
__device__ __forceinline__ void stage32_128(const _Float16* __restrict__ G,
                                            int K, int rowbase, int kt,
                                            char* region, int t) {
#pragma unroll
  for (int s = 0; s < 2; ++s) {
    const int row = s * 64 + (t >> 2);
    const int srcc = ((t & 3) ^ ((row >> 1) & 3)) * 8;  // inverse swizzle
    gld16(G + (size_t)(rowbase + row) * K + kt + srcc,
          region + s * 4096 + (t & ~63) * 16);
  }
}

// stage a 64-row x 32-f16 tile = 1 sweep (for split kv B-tiles)
__device__ __forceinline__ void stage32_64(const _Float16* __restrict__ G,
                                           int K, int rowbase, int kt,
                                           char* region, int t) {
  const int row = t >> 2;
  const int srcc = ((t & 3) ^ ((row >> 1) & 3)) * 8;
  gld16(G + (size_t)(rowbase + row) * K + kt + srcc, region + (t & ~63) * 16);
}

// EPI 0: tileN<4 -> fused softmax(q) -> oQ[16384][512];
//        tileN>=4 -> head h=tileN-4, B-cols [k_h | v_h]; epilogue computes
//        64x64 partial ek^T v via MFMA + colsums -> ctxpart(f16)/colpart.
// EPI 1: +bias, f32 out ldc=1024 (A=softq, BT=CW^T per batch via bstride).
template <int EPI>
__global__ __launch_bounds__(256, 3) void gemm128(
    const _Float16* __restrict__ A, const _Float16* __restrict__ BT, int K,
    int NTN, int bstride, _Float16* __restrict__ oQ,
    _Float16* __restrict__ ctxpart, float* __restrict__ colpart,
    float* __restrict__ oC, const float* __restrict__ bias) {
  __shared__ char lds[49152];
  const int t = threadIdx.x;
  const int l = t & 63, w = t >> 6;
  const int wm = w >> 1, wn = w & 1;  // wave -> 64x64 quadrant
  const int fr = l & 15, qq = l >> 4;
  const int cswz = ((qq ^ ((fr >> 1) & 3)) * 16);  // swizzled chunk byte off

  // T1: bijective XCD chunking (nwg % 8 == 0), tileM-major within chunk
  const int nwg = gridDim.x;
  const int cpx = nwg >> 3;
  const int wg = (blockIdx.x & 7) * cpx + (blockIdx.x >> 3);
  const int tileM = wg / NTN, tileN = wg - tileM * NTN;
  const int mbase = tileM * 128, nbase = tileN * 128;
  BT += (size_t)(tileM >> 6) * bstride;  // per-batch B (0 for GEMM1)

  const int NT = K >> 5;
  f32x4 acc[4][4] = {};
  half8 a[4], b[4];

  // stage both operands of K-tile `tile` into buffer (tile%3); 4 loads/thread
  auto STG = [&](int tile) {
    int kt = tile * 32;
    if (kt > K - 32) kt = K - 32;  // tail clamp: identical issue counts
    char* base = lds + (tile % 3) * 16384;
    stage32_128(A, K, mbase, kt, base, t);  // 2 loads
    if (EPI == 1 || tileN < 4) {
      stage32_128(BT, K, nbase, kt, base + 8192, t);  // 2 loads
    } else {
      const int h = tileN - 4;
      stage32_64(BT, K, 512 + h * 64, kt, base + 8192, t);         // k_h
      stage32_64(BT, K, 1024 + h * 64, kt, base + 8192 + 4096, t); // v_h
    }
  };

  // prologue: tiles 0,1 (8 loads); vmcnt(4) -> tile0 resident, tile1 in flight
  STG(0);
  STG(1);
  asm volatile("s_waitcnt vmcnt(4)" ::: "memory");
  __builtin_amdgcn_s_barrier();

  for (int t2 = 0; t2 < NT; ++t2) {
    const char* bufc = lds + (t2 % 3) * 16384;
    const char* ldsA = bufc;
    const char* ldsB = bufc + 8192;
    // issue 2-ahead staging (buf (t2+2)%3 is free: last read at iter t2-1)
    STG(t2 + 2);
    // frag reads from current buffer
#pragma unroll
    for (int mi = 0; mi < 4; ++mi)
      a[mi] = *(const half8*)(ldsA + (wm * 64 + mi * 16 + fr) * 64 + cswz);
#pragma unroll
    for (int ni = 0; ni < 4; ++ni)
      b[ni] = *(const half8*)(ldsB + (wn * 64 + ni * 16 + fr) * 64 + cswz);
    __builtin_amdgcn_s_setprio(1);
#pragma unroll
    for (int mi = 0; mi < 4; ++mi)
#pragma unroll
      for (int ni = 0; ni < 2; ++ni)
        acc[mi][ni] = __builtin_amdgcn_mfma_f32_16x16x32_f16(
            a[mi], b[ni], acc[mi][ni], 0, 0, 0);
    __builtin_amdgcn_s_setprio(0);
    // lgkm0: this wave's reads of cur done (overwrite comes at iter t2+1's
    // STG(t2+3), issued only after BAR). vmcnt(4): tile t2+1 resident
    // (only t2+2's 4 loads may remain in flight). BAR publishes both.
    asm volatile("s_waitcnt vmcnt(4) lgkmcnt(0)" ::: "memory");
    __builtin_amdgcn_s_barrier();
    __builtin_amdgcn_s_setprio(1);
#pragma unroll
    for (int mi = 0; mi < 4; ++mi)
#pragma unroll
      for (int ni = 2; ni < 4; ++ni)
        acc[mi][ni] = __builtin_amdgcn_mfma_f32_16x16x32_f16(
            a[mi], b[ni], acc[mi][ni], 0, 0, 0);
    __builtin_amdgcn_s_setprio(0);
  }
  // drain tail prefetch (targets buf regions reused below) + publish
  asm volatile("s_waitcnt vmcnt(0)" ::: "memory");
  __builtin_amdgcn_s_barrier();

  // C/D layout: col = lane&15 (=fr), row = (lane>>4)*4 + reg (=qq*4+r)
  if (EPI == 0) {
    if (tileN < 4) {
      // fused softmax over head dim (4 in-reg + shfl_xor<16), store softq
      const int gcol0 = nbase + wn * 64;
#pragma unroll
      for (int mi = 0; mi < 4; ++mi) {
        const int grow = mbase + wm * 64 + mi * 16 + qq * 4;
        float e[4][4], rs[4];
#pragma unroll
        for (int r = 0; r < 4; ++r) {
          float s = 0.f;
#pragma unroll
          for (int ni = 0; ni < 4; ++ni) {
            e[ni][r] = __expf(acc[mi][ni][r]);
            s += e[ni][r];
          }
#pragma unroll
          for (int off = 1; off < 16; off <<= 1) s += __shfl_xor(s, off, 64);
          rs[r] = 1.f / s;
        }
#pragma unroll
        for (int ni = 0; ni < 4; ++ni) {
          const int gcol = gcol0 + ni * 16 + fr;
#pragma unroll
          for (int r = 0; r < 4; ++r)
            oQ[(size_t)(grow + r) * 512 + gcol] = (_Float16)(e[ni][r] * rs[r]);
        }
      }
    } else {
      // kv path (MFMA ctx): local cols 0-63 = k logits (wn=0), 64-127 = v.
      const int h = tileN - 4;
      float* credu = (float*)(lds + 32768);  // [2][64] colsum partials
      // exp on k-quadrant + in-register colsum (sum over this wave's 64 n)
      if (wn == 0) {
#pragma unroll
        for (int mi = 0; mi < 4; ++mi)
#pragma unroll
          for (int ni = 0; ni < 4; ++ni) {
            f32x4 e4;
#pragma unroll
            for (int r = 0; r < 4; ++r) e4[r] = __expf(acc[mi][ni][r]);
            acc[mi][ni] = e4;
          }
        float s[4] = {};
#pragma unroll
        for (int ni = 0; ni < 4; ++ni) {
#pragma unroll
          for (int mi = 0; mi < 4; ++mi)
#pragma unroll
            for (int r = 0; r < 4; ++r) s[ni] += acc[mi][ni][r];
          s[ni] += __shfl_xor(s[ni], 16, 64);
          s[ni] += __shfl_xor(s[ni], 32, 64);
        }
        if (l < 16) {
#pragma unroll
          for (int ni = 0; ni < 4; ++ni) credu[wm * 64 + ni * 16 + fr] = s[ni];
        }
      }
      // transposed f16 dump: ekT[64 c][128 n] @lds+0, vT @lds+16384;
      // swizzle: byte ^= ((c&15)<<4) on the n-offset (16B-chunk involution)
      {
        char* dst8 = lds + (wn ? 16384 : 0);
#pragma unroll
        for (int mi = 0; mi < 4; ++mi) {
          const int nb = (wm * 64 + mi * 16 + qq * 4) * 2;  // n byte offset
#pragma unroll
          for (int ni = 0; ni < 4; ++ni) {
            const int c = ni * 16 + fr;
            half4 pk = {(_Float16)acc[mi][ni][0], (_Float16)acc[mi][ni][1],
                        (_Float16)acc[mi][ni][2], (_Float16)acc[mi][ni][3]};
            *(half4*)(dst8 + c * 256 + (nb ^ ((c & 15) << 4))) = pk;
          }
        }
      }
      __syncthreads();
      // MFMA: D[d][e] = sum_n ekT[d][n]*vT[e][n]; wave w -> e in [w*16,+16)
      half8 bf[4];
      const int erow = w * 16 + fr;
#pragma unroll
      for (int kk = 0; kk < 4; ++kk)
        bf[kk] = *(const half8*)(lds + 16384 + erow * 256 +
                                 ((kk * 64 + qq * 16) ^ ((erow & 15) << 4)));
      f32x4 dacc[4] = {};
#pragma unroll
      for (int mi = 0; mi < 4; ++mi) {
        const int drow = mi * 16 + fr;
#pragma unroll
        for (int kk = 0; kk < 4; ++kk) {
          half8 af = *(const half8*)(lds + drow * 256 +
                                     ((kk * 64 + qq * 16) ^ ((drow & 15) << 4)));
          dacc[mi] =
              __builtin_amdgcn_mfma_f32_16x16x32_f16(af, bf[kk], dacc[mi], 0, 0, 0);
        }
      }
      const int bh = (tileM >> 6) * 8 + h, chunk = tileM & 63;
      _Float16* cp = ctxpart + ((size_t)bh * 64 + chunk) * 4096;
#pragma unroll
      for (int mi = 0; mi < 4; ++mi)
#pragma unroll
        for (int r = 0; r < 4; ++r)
          cp[(mi * 16 + qq * 4 + r) * 64 + w * 16 + fr] =
              (_Float16)dacc[mi][r];
      if (t < 16) {
        f32x4 c0 = *(const f32x4*)&credu[t * 4];
        f32x4 c1 = *(const f32x4*)&credu[64 + t * 4];
        *(f32x4*)&colpart[((size_t)bh * 64 + chunk) * 64 + t * 4] = c0 + c1;
      }
    }
  } else {
#pragma unroll
    for (int mi = 0; mi < 4; ++mi) {
      const int grow = mbase + wm * 64 + mi * 16 + qq * 4;
#pragma unroll
      for (int ni = 0; ni < 4; ++ni) {
        const int gcol = nbase + wn * 64 + ni * 16 + fr;
        const float bb = bias[gcol];
#pragma unroll
        for (int r = 0; r < 4; ++r)
          oC[(size_t)(grow + r) * 1024 + gcol] = acc[mi][ni][r] + bb;
      }
    }
  }
}

// Merged reduce + CW^T: block = (bh, d). Reduces 64 chunk-partials (f16),
// divides by colsum, then CW^T[b][o][h*64+d] = sum_e crow[e]*Wout[h*64+e][o].
__global__ __launch_bounds__(256) void ctxw_kernel(
    const _Float16* __restrict__ ctxpart, const float* __restrict__ colpart,
    const float* __restrict__ Wout, _Float16* __restrict__ cwT) {
  __shared__ float part[4][64];
  __shared__ float csp[64];
  __shared__ float crow[64];
  const int blk = blockIdx.x;
  const int bh = blk >> 6, d = blk & 63;
  const int b = bh >> 3, h = bh & 7;
  const int t = threadIdx.x;
  const int e = t & 63, cq = t >> 6;
  float p = 0.f;
#pragma unroll
  for (int cc = 0; cc < 16; ++cc)
    p += (float)ctxpart[((size_t)bh * 64 + cq * 16 + cc) * 4096 + d * 64 + e];
  part[cq][e] = p;
  if (t >= 64 && t < 128)
    csp[t - 64] = colpart[((size_t)bh * 64 + (t - 64)) * 64 + d];
  __syncthreads();
  if (t < 64) {
    float csum = 0.f;
#pragma unroll
    for (int c = 0; c < 64; ++c) csum += csp[c];
    crow[t] = (part[0][t] + part[1][t] + part[2][t] + part[3][t]) / csum;
  }
  __syncthreads();
  float acc[4] = {};
  for (int e2 = 0; e2 < 64; ++e2) {
    const float c = crow[e2];
    const float* wr = Wout + (size_t)(h * 64 + e2) * 1024 + t;
#pragma unroll
    for (int j = 0; j < 4; ++j) acc[j] += c * wr[j * 256];
  }
  _Float16* dst = cwT + (size_t)b * 524288 + (size_t)t * 512 + h * 64 + d;
#pragma unroll
  for (int j = 0; j < 4; ++j) dst[(size_t)j * 256 * 512] = (_Float16)acc[j];
}

extern "C" void kernel_launch(void* const* d_in, const int* in_sizes, int n_in,
                              void* d_out, int out_size, void* d_ws, size_t ws_size,
                              hipStream_t stream) {
  const float* x = (const float*)d_in[0];
  const float* Wqkv = (const float*)d_in[1];
  const float* Wout = (const float*)d_in[2];
  const float* bout = (const float*)d_in[3];
  float* out = (float*)d_out;
  char* ws = (char*)d_ws;

  _Float16* xb = (_Float16*)(ws + WS_XB);
  _Float16* wqkvT = (_Float16*)(ws + WS_WQKVT);
  _Float16* cwT = (_Float16*)(ws + WS_CWT);
  _Float16* sq = (_Float16*)(ws + WS_SQ);
  _Float16* ctxpart = (_Float16*)(ws + WS_CTXPART);
  float* colpart = (float*)(ws + WS_COLPART);

  // 1) fused converts (x cvt + LDS-tiled W_qkv transpose)
  prep_kernel<<<16768, 256, 0, stream>>>(x, Wqkv, xb, wqkvT);
  // 2) qkv projection; q blocks -> fused softmax -> sq; kv blocks -> fused
  //    MFMA partial-context -> ctxpart(f16)/colpart
  gemm128<0><<<1536, 256, 0, stream>>>(xb, wqkvT, 1024, 12, 0, sq, ctxpart,
                                       colpart, nullptr, nullptr);
  // 3) reduce + CW^T = (ctx @ W_out)^T per batch
  ctxw_kernel<<<1024, 256, 0, stream>>>(ctxpart, colpart, Wout, cwT);
  // 4) out = softq @ CW + b  (M=16384,N=1024,K=512; B selected per batch)
  gemm128<1><<<1024, 256, 0, stream>>>(sq, cwT, 512, 8, 524288, nullptr,
                                       nullptr, nullptr, out, bout);
}

// Round 15
// 131.142 us; speedup vs baseline: 1.0364x; 1.0364x over previous
//
#include <hip/hip_runtime.h>
#include <stdint.h>

// LinearAttention: x[2,8192,1024] -> qkv proj -> per-head softmaxes ->
// context = softmax_n(k)^T v -> out = softmax_d(q) @ ctx -> @ W_out + b.
//
// R15 = R13 verbatim (measured best, 131.3us). R14's BK=32 triple-buffer
// regressed (occupancy +40% but per-tile sync overhead doubled); reverted.
// Structure: 128x128/BK64/4-wave/64KB LDS, 2 blocks/CU GEMM (4x-confirmed
// local optimum ~814 TF); ctx fused into GEMM1 (MFMA epilogue, f16
// partials); fused softmax(q); out = softq @ (ctx@W_out) per-batch CW^T;
// prep: x cvt + LDS-tiled W_qkv transpose.

typedef _Float16 half4 __attribute__((ext_vector_type(4)));
typedef _Float16 half8 __attribute__((ext_vector_type(8)));
typedef float f32x4 __attribute__((ext_vector_type(4)));

// ---- workspace byte offsets ----
#define WS_XB 0UL             // x as f16           [16384][1024]   33.55MB
#define WS_WQKVT 33554432UL   // W_qkv^T f16        [1536][1024]     3.15MB
#define WS_CWT 37748736UL     // CW^T f16           [2][1024][512]   2.10MB
#define WS_CTXPART 54525952UL // ctx partials f16   [16][64][4096]   8.39MB
#define WS_COLPART 71303168UL // colsum partials f32[16][64][64]     0.26MB
#define WS_SQ 88080384UL      // softmax(q) f16     [16384][512]    16.78MB

__device__ __forceinline__ void gld16(const void* g, void* l) {
  // async global->LDS, 16B per lane; LDS dest = wave-uniform base + lane*16
  __builtin_amdgcn_global_load_lds(
      (const __attribute__((address_space(1))) unsigned int*)g,
      (__attribute__((address_space(3))) unsigned int*)l, 16, 0, 0);
}

// Fused prep: cvt x (f32->f16) + LDS-tiled transpose+cvt of W_qkv.
// Blocks [0,16384): x cvt. Blocks [16384,16768): 64x64 W-tiles, 16x24 grid.
__global__ void prep_kernel(const float* __restrict__ x,
                            const float* __restrict__ Wqkv,
                            _Float16* __restrict__ xb,
                            _Float16* __restrict__ wqkvT) {
  const int blk = blockIdx.x;
  const int t = threadIdx.x;
  if (blk < 16384) {
    int i = blk * 256 + t;  // 4 f32 per thread
    f32x4 v = *(const f32x4*)(x + (size_t)i * 4);
    half4 h = {(_Float16)v[0], (_Float16)v[1], (_Float16)v[2], (_Float16)v[3]};
    *(half4*)(xb + (size_t)i * 4) = h;
  } else {
    __shared__ float sT[64 * 65];  // transposed tile, pad 65 vs bank conflicts
    const int tb = blk - 16384;
    const int r0 = (tb & 15) * 64, c0 = (tb >> 4) * 64;  // W rows / cols
    const int lr = t >> 4, lc4 = (t & 15) * 4;
#pragma unroll
    for (int s = 0; s < 4; ++s) {
      const int row = s * 16 + lr;  // coalesced: lanes sweep consecutive cols
      f32x4 v = *(const f32x4*)&Wqkv[(size_t)(r0 + row) * 1536 + c0 + lc4];
#pragma unroll
      for (int j = 0; j < 4; ++j) sT[(lc4 + j) * 65 + row] = v[j];
    }
    __syncthreads();
#pragma unroll
    for (int s = 0; s < 4; ++s) {
      const int cl = s * 16 + lr;  // output row (W col), lanes sweep W rows
      half4 o = {(_Float16)sT[cl * 65 + lc4], (_Float16)sT[cl * 65 + lc4 + 1],
                 (_Float16)sT[cl * 65 + lc4 + 2],
                 (_Float16)sT[cl * 65 + lc4 + 3]};
      *(half4*)&wqkvT[(size_t)(c0 + cl) * 1024 + r0 + lc4] = o;
    }
  }
}

// ---------------- 128x128 BK=64 co-resident GEMM (R11-measured) ------------
// A[M][K] f16 row-major, BT[N][K] f16 row-major. 256 threads = 4 waves (2Mx2N),
// per-wave output 64x64 (acc[4][4]). LDS: 2 dbuf x (A 16KB + B 16KB) = 64KB.
// Tile layout [128 rows][128B], XOR swizzle byte ^= ((row&7)<<4); staged
// linearly via global_load_lds with inverse-swizzled global source column.

// stage one full 128x64-f16 tile region = 4 sweeps x 1 gld16/thread
__device__ __forceinline__ void stage_tile(const _Float16* __restrict__ G, int K,
                                           int rowbase, int kt, char* region,
                                           int t) {
  char* wbase = region + (t & ~63) * 16;  // + lane*16 done by HW
#pragma unroll
  for (int q = 0; q < 4; ++q) {
    const int row = q * 32 + (t >> 3);
    const int col8 = ((t & 7) ^ (row & 7)) * 8;  // inverse-swizzled f16 col
    gld16(G + (size_t)(rowbase + row) * K + kt + col8, wbase + q * 4096);
  }
}

// stage a 64-row tile region = 2 sweeps (for split kv B-tiles)
__device__ __forceinline__ void stage_tile64(const _Float16* __restrict__ G,
                                             int K, int rowbase, int kt,
                                             char* region, int t) {
  char* wbase = region + (t & ~63) * 16;
#pragma unroll
  for (int q = 0; q < 2; ++q) {
    const int row = q * 32 + (t >> 3);
    const int col8 = ((t & 7) ^ (row & 7)) * 8;
    gld16(G + (size_t)(rowbase + row) * K + kt + col8, wbase + q * 4096);
  }
}

// EPI 0: tileN<4 -> fused softmax(q) -> oQ[16384][512];
//        tileN>=4 -> head h=tileN-4, B-cols [k_h | v_h]; epilogue computes
//        64x64 partial ek^T v via MFMA + colsums -> ctxpart(f16)/colpart.
// EPI 1: +bias, f32 out ldc=1024 (A=softq, BT=CW^T per batch via bstride).
template <int EPI>
__global__ __launch_bounds__(256, 2) void gemm128(
    const _Float16* __restrict__ A, const _Float16* __restrict__ BT, int K,
    int NTN, int bstride, _Float16* __restrict__ oQ,
    _Float16* __restrict__ ctxpart, float* __restrict__ colpart,
    float* __restrict__ oC, const float* __restrict__ bias) {
  __shared__ char lds[65536];
  const int t = threadIdx.x;
  const int l = t & 63, w = t >> 6;
  const int wm = w >> 1, wn = w & 1;  // wave -> 64x64 quadrant
  const int fr = l & 15, qq = l >> 4;
  const int swzx = (fr & 7) << 4;

  // T1: bijective XCD chunking (nwg % 8 == 0), tileM-major within chunk
  const int nwg = gridDim.x;
  const int cpx = nwg >> 3;
  const int wg = (blockIdx.x & 7) * cpx + (blockIdx.x >> 3);
  const int tileM = wg / NTN, tileN = wg - tileM * NTN;
  const int mbase = tileM * 128, nbase = tileN * 128;
  BT += (size_t)(tileM >> 6) * bstride;  // per-batch B (0 for GEMM1)

  const int NT = K >> 6;
  f32x4 acc[4][4] = {};
  half8 a[4][2], b[4][2];

  // stage both operands of K-tile `tile` into buffer (tile&1); 8 loads/thread
  auto STG = [&](int tile) {
    int kt = tile * 64;
    if (kt > K - 64) kt = K - 64;  // tail clamp: identical issue counts
    char* base = lds + ((tile & 1) << 15);
    stage_tile(A, K, mbase, kt, base, t);  // 4 loads
    if (EPI == 1 || tileN < 4) {
      stage_tile(BT, K, nbase, kt, base + 16384, t);  // 4 loads
    } else {
      const int h = tileN - 4;
      stage_tile64(BT, K, 512 + h * 64, kt, base + 16384, t);          // k_h
      stage_tile64(BT, K, 1024 + h * 64, kt, base + 16384 + 8192, t);  // v_h
    }
  };

  // prologue: tile0 + tile1 (16 loads/thread); vmcnt(8) -> tile0 resident
  STG(0);
  STG(1);
  asm volatile("s_waitcnt vmcnt(8)" ::: "memory");
  __builtin_amdgcn_s_barrier();

  for (int t2 = 0; t2 < NT; ++t2) {
    const char* ldsA = lds + ((t2 & 1) << 15);
    const char* ldsB = ldsA + 16384;
    // ph0: stage tile t2+1 -> other buffer (prev readers drained at ph1's
    // lgkmcnt(0) before BAR_b); then all frag reads from cur.
    STG(t2 + 1);
#pragma unroll
    for (int mi = 0; mi < 4; ++mi)
#pragma unroll
      for (int kk = 0; kk < 2; ++kk) {
        int off = (wm * 64 + mi * 16 + fr) * 128 + ((kk * 64 + qq * 16) ^ swzx);
        a[mi][kk] = *(const half8*)(ldsA + off);
      }
#pragma unroll
    for (int ni = 0; ni < 4; ++ni)
#pragma unroll
      for (int kk = 0; kk < 2; ++kk) {
        int off = (wn * 64 + ni * 16 + fr) * 128 + ((kk * 64 + qq * 16) ^ swzx);
        b[ni][kk] = *(const half8*)(ldsB + off);
      }
    __builtin_amdgcn_s_barrier();  // BAR_a
    __builtin_amdgcn_s_setprio(1);
#pragma unroll
    for (int mi = 0; mi < 4; ++mi)
#pragma unroll
      for (int ni = 0; ni < 2; ++ni)
#pragma unroll
        for (int kk = 0; kk < 2; ++kk)
          acc[mi][ni] = __builtin_amdgcn_mfma_f32_16x16x32_f16(
              a[mi][kk], b[ni][kk], acc[mi][ni], 0, 0, 0);
    __builtin_amdgcn_s_setprio(0);
    // ph1: drain this tile's ds_reads so next iter's STG->other is race-free;
    // drain stage loads (t2+1).
    asm volatile("s_waitcnt vmcnt(0) lgkmcnt(0)" ::: "memory");
    __builtin_amdgcn_s_barrier();  // BAR_b
    __builtin_amdgcn_s_setprio(1);
#pragma unroll
    for (int mi = 0; mi < 4; ++mi)
#pragma unroll
      for (int ni = 2; ni < 4; ++ni)
#pragma unroll
        for (int kk = 0; kk < 2; ++kk)
          acc[mi][ni] = __builtin_amdgcn_mfma_f32_16x16x32_f16(
              a[mi][kk], b[ni][kk], acc[mi][ni], 0, 0, 0);
    __builtin_amdgcn_s_setprio(0);
  }
  // no gld16/ds_read in flight here (drained at final ph1); LDS reusable.

  // C/D layout: col = lane&15 (=fr), row = (lane>>4)*4 + reg (=qq*4+r)
  if (EPI == 0) {
    if (tileN < 4) {
      // fused softmax over head dim (4 in-reg + shfl_xor<16), store softq
      const int gcol0 = nbase + wn * 64;
#pragma unroll
      for (int mi = 0; mi < 4; ++mi) {
        const int grow = mbase + wm * 64 + mi * 16 + qq * 4;
        float e[4][4], rs[4];
#pragma unroll
        for (int r = 0; r < 4; ++r) {
          float s = 0.f;
#pragma unroll
          for (int ni = 0; ni < 4; ++ni) {
            e[ni][r] = __expf(acc[mi][ni][r]);
            s += e[ni][r];
          }
#pragma unroll
          for (int off = 1; off < 16; off <<= 1) s += __shfl_xor(s, off, 64);
          rs[r] = 1.f / s;
        }
#pragma unroll
        for (int ni = 0; ni < 4; ++ni) {
          const int gcol = gcol0 + ni * 16 + fr;
#pragma unroll
          for (int r = 0; r < 4; ++r)
            oQ[(size_t)(grow + r) * 512 + gcol] = (_Float16)(e[ni][r] * rs[r]);
        }
      }
    } else {
      // kv path (MFMA ctx): local cols 0-63 = k logits (wn=0), 64-127 = v.
      const int h = tileN - 4;
      float* credu = (float*)(lds + 32768);  // [2][64] colsum partials
      // exp on k-quadrant + in-register colsum (sum over this wave's 64 n)
      if (wn == 0) {
#pragma unroll
        for (int mi = 0; mi < 4; ++mi)
#pragma unroll
          for (int ni = 0; ni < 4; ++ni) {
            f32x4 e4;
#pragma unroll
            for (int r = 0; r < 4; ++r) e4[r] = __expf(acc[mi][ni][r]);
            acc[mi][ni] = e4;
          }
        float s[4] = {};
#pragma unroll
        for (int ni = 0; ni < 4; ++ni) {
#pragma unroll
          for (int mi = 0; mi < 4; ++mi)
#pragma unroll
            for (int r = 0; r < 4; ++r) s[ni] += acc[mi][ni][r];
          s[ni] += __shfl_xor(s[ni], 16, 64);
          s[ni] += __shfl_xor(s[ni], 32, 64);
        }
        if (l < 16) {
#pragma unroll
          for (int ni = 0; ni < 4; ++ni) credu[wm * 64 + ni * 16 + fr] = s[ni];
        }
      }
      // transposed f16 dump: ekT[64 c][128 n] @lds+0, vT @lds+16384;
      // swizzle: byte ^= ((c&15)<<4) on the n-offset (16B-chunk involution)
      {
        char* dst8 = lds + (wn ? 16384 : 0);
#pragma unroll
        for (int mi = 0; mi < 4; ++mi) {
          const int nb = (wm * 64 + mi * 16 + qq * 4) * 2;  // n byte offset
#pragma unroll
          for (int ni = 0; ni < 4; ++ni) {
            const int c = ni * 16 + fr;
            half4 pk = {(_Float16)acc[mi][ni][0], (_Float16)acc[mi][ni][1],
                        (_Float16)acc[mi][ni][2], (_Float16)acc[mi][ni][3]};
            *(half4*)(dst8 + c * 256 + (nb ^ ((c & 15) << 4))) = pk;
          }
        }
      }
      __syncthreads();
      // MFMA: D[d][e] = sum_n ekT[d][n]*vT[e][n]; wave w -> e in [w*16,+16)
      half8 bf[4];
      const int erow = w * 16 + fr;
#pragma unroll
      for (int kk = 0; kk < 4; ++kk)
        bf[kk] = *(const half8*)(lds + 16384 + erow * 256 +
                                 ((kk * 64 + qq * 16) ^ ((erow & 15) << 4)));
      f32x4 dacc[4] = {};
#pragma unroll
      for (int mi = 0; mi < 4; ++mi) {
        const int drow = mi * 16 + fr;
#pragma unroll
        for (int kk = 0; kk < 4; ++kk) {
          half8 af = *(const half8*)(lds + drow * 256 +
                                     ((kk * 64 + qq * 16) ^ ((drow & 15) << 4)));
          dacc[mi] =
              __builtin_amdgcn_mfma_f32_16x16x32_f16(af, bf[kk], dacc[mi], 0, 0, 0);
        }
      }
      const int bh = (tileM >> 6) * 8 + h, chunk = tileM & 63;
      _Float16* cp = ctxpart + ((size_t)bh * 64 + chunk) * 4096;
#pragma unroll
      for (int mi = 0; mi < 4; ++mi)
#pragma unroll
        for (int r = 0; r < 4; ++r)
          cp[(mi * 16 + qq * 4 + r) * 64 + w * 16 + fr] =
              (_Float16)dacc[mi][r];
      if (t < 16) {
        f32x4 c0 = *(const f32x4*)&credu[t * 4];
        f32x4 c1 = *(const f32x4*)&credu[64 + t * 4];
        *(f32x4*)&colpart[((size_t)bh * 64 + chunk) * 64 + t * 4] = c0 + c1;
      }
    }
  } else {
#pragma unroll
    for (int mi = 0; mi < 4; ++mi) {
      const int grow = mbase + wm * 64 + mi * 16 + qq * 4;
#pragma unroll
      for (int ni = 0; ni < 4; ++ni) {
        const int gcol = nbase + wn * 64 + ni * 16 + fr;
        const float bb = bias[gcol];
#pragma unroll
        for (int r = 0; r < 4; ++r)
          oC[(size_t)(grow + r) * 1024 + gcol] = acc[mi][ni][r] + bb;
      }
    }
  }
}

// Merged reduce + CW^T: block = (bh, d). Reduces 64 chunk-partials (f16),
// divides by colsum, then CW^T[b][o][h*64+d] = sum_e crow[e]*Wout[h*64+e][o].
__global__ __launch_bounds__(256) void ctxw_kernel(
    const _Float16* __restrict__ ctxpart, const float* __restrict__ colpart,
    const float* __restrict__ Wout, _Float16* __restrict__ cwT) {
  __shared__ float part[4][64];
  __shared__ float csp[64];
  __shared__ float crow[64];
  const int blk = blockIdx.x;
  const int bh = blk >> 6, d = blk & 63;
  const int b = bh >> 3, h = bh & 7;
  const int t = threadIdx.x;
  const int e = t & 63, cq = t >> 6;
  float p = 0.f;
#pragma unroll
  for (int cc = 0; cc < 16; ++cc)
    p += (float)ctxpart[((size_t)bh * 64 + cq * 16 + cc) * 4096 + d * 64 + e];
  part[cq][e] = p;
  if (t >= 64 && t < 128)
    csp[t - 64] = colpart[((size_t)bh * 64 + (t - 64)) * 64 + d];
  __syncthreads();
  if (t < 64) {
    float csum = 0.f;
#pragma unroll
    for (int c = 0; c < 64; ++c) csum += csp[c];
    crow[t] = (part[0][t] + part[1][t] + part[2][t] + part[3][t]) / csum;
  }
  __syncthreads();
  float acc[4] = {};
  for (int e2 = 0; e2 < 64; ++e2) {
    const float c = crow[e2];
    const float* wr = Wout + (size_t)(h * 64 + e2) * 1024 + t;
#pragma unroll
    for (int j = 0; j < 4; ++j) acc[j] += c * wr[j * 256];
  }
  _Float16* dst = cwT + (size_t)b * 524288 + (size_t)t * 512 + h * 64 + d;
#pragma unroll
  for (int j = 0; j < 4; ++j) dst[(size_t)j * 256 * 512] = (_Float16)acc[j];
}

extern "C" void kernel_launch(void* const* d_in, const int* in_sizes, int n_in,
                              void* d_out, int out_size, void* d_ws, size_t ws_size,
                              hipStream_t stream) {
  const float* x = (const float*)d_in[0];
  const float* Wqkv = (const float*)d_in[1];
  const float* Wout = (const float*)d_in[2];
  const float* bout = (const float*)d_in[3];
  float* out = (float*)d_out;
  char* ws = (char*)d_ws;

  _Float16* xb = (_Float16*)(ws + WS_XB);
  _Float16* wqkvT = (_Float16*)(ws + WS_WQKVT);
  _Float16* cwT = (_Float16*)(ws + WS_CWT);
  _Float16* sq = (_Float16*)(ws + WS_SQ);
  _Float16* ctxpart = (_Float16*)(ws + WS_CTXPART);
  float* colpart = (float*)(ws + WS_COLPART);

  // 1) fused converts (x cvt + LDS-tiled W_qkv transpose)
  prep_kernel<<<16768, 256, 0, stream>>>(x, Wqkv, xb, wqkvT);
  // 2) qkv projection; q blocks -> fused softmax -> sq; kv blocks -> fused
  //    MFMA partial-context -> ctxpart(f16)/colpart
  gemm128<0><<<1536, 256, 0, stream>>>(xb, wqkvT, 1024, 12, 0, sq, ctxpart,
                                       colpart, nullptr, nullptr);
  // 3) reduce + CW^T = (ctx @ W_out)^T per batch
  ctxw_kernel<<<1024, 256, 0, stream>>>(ctxpart, colpart, Wout, cwT);
  // 4) out = softq @ CW + b  (M=16384,N=1024,K=512; B selected per batch)
  gemm128<1><<<1024, 256, 0, stream>>>(sq, cwT, 512, 8, 524288, nullptr,
                                       nullptr, nullptr, out, bout);
}

// Round 16
// 129.930 us; speedup vs baseline: 1.0461x; 1.0093x over previous
//
#include <hip/hip_runtime.h>
#include <stdint.h>

// LinearAttention: x[2,8192,1024] -> qkv proj -> per-head softmaxes ->
// context = softmax_n(k)^T v -> out = softmax_d(q) @ ctx -> @ W_out + b.
//
// R16 = R13 + single-barrier K-loop (BK=64 geometry unchanged):
//   STG(t2+1)->other; reads(cur); MFMA1; vmcnt(0)+lgkm(0); BAR; MFMA2.
// Proof: lgkm0@BAR drains cur-reads before STG(t2+2)->cur (post-BAR);
// vmcnt0@BAR makes tile t2+1 resident before its reads; MFMA2 is reg-only.
// Prologue stages tile0 once (R7's tile1 double-stage removed).
// Rest = R13: ctx fused into GEMM1 (MFMA epilogue, f16 partials), fused
// softmax(q), out = softq @ (ctx@W_out) per-batch CW^T, LDS-tiled prep.

typedef _Float16 half4 __attribute__((ext_vector_type(4)));
typedef _Float16 half8 __attribute__((ext_vector_type(8)));
typedef float f32x4 __attribute__((ext_vector_type(4)));

// ---- workspace byte offsets ----
#define WS_XB 0UL             // x as f16           [16384][1024]   33.55MB
#define WS_WQKVT 33554432UL   // W_qkv^T f16        [1536][1024]     3.15MB
#define WS_CWT 37748736UL     // CW^T f16           [2][1024][512]   2.10MB
#define WS_CTXPART 54525952UL // ctx partials f16   [16][64][4096]   8.39MB
#define WS_COLPART 71303168UL // colsum partials f32[16][64][64]     0.26MB
#define WS_SQ 88080384UL      // softmax(q) f16     [16384][512]    16.78MB

__device__ __forceinline__ void gld16(const void* g, void* l) {
  // async global->LDS, 16B per lane; LDS dest = wave-uniform base + lane*16
  __builtin_amdgcn_global_load_lds(
      (const __attribute__((address_space(1))) unsigned int*)g,
      (__attribute__((address_space(3))) unsigned int*)l, 16, 0, 0);
}

// Fused prep: cvt x (f32->f16) + LDS-tiled transpose+cvt of W_qkv.
// Blocks [0,16384): x cvt. Blocks [16384,16768): 64x64 W-tiles, 16x24 grid.
__global__ void prep_kernel(const float* __restrict__ x,
                            const float* __restrict__ Wqkv,
                            _Float16* __restrict__ xb,
                            _Float16* __restrict__ wqkvT) {
  const int blk = blockIdx.x;
  const int t = threadIdx.x;
  if (blk < 16384) {
    int i = blk * 256 + t;  // 4 f32 per thread
    f32x4 v = *(const f32x4*)(x + (size_t)i * 4);
    half4 h = {(_Float16)v[0], (_Float16)v[1], (_Float16)v[2], (_Float16)v[3]};
    *(half4*)(xb + (size_t)i * 4) = h;
  } else {
    __shared__ float sT[64 * 65];  // transposed tile, pad 65 vs bank conflicts
    const int tb = blk - 16384;
    const int r0 = (tb & 15) * 64, c0 = (tb >> 4) * 64;  // W rows / cols
    const int lr = t >> 4, lc4 = (t & 15) * 4;
#pragma unroll
    for (int s = 0; s < 4; ++s) {
      const int row = s * 16 + lr;  // coalesced: lanes sweep consecutive cols
      f32x4 v = *(const f32x4*)&Wqkv[(size_t)(r0 + row) * 1536 + c0 + lc4];
#pragma unroll
      for (int j = 0; j < 4; ++j) sT[(lc4 + j) * 65 + row] = v[j];
    }
    __syncthreads();
#pragma unroll
    for (int s = 0; s < 4; ++s) {
      const int cl = s * 16 + lr;  // output row (W col), lanes sweep W rows
      half4 o = {(_Float16)sT[cl * 65 + lc4], (_Float16)sT[cl * 65 + lc4 + 1],
                 (_Float16)sT[cl * 65 + lc4 + 2],
                 (_Float16)sT[cl * 65 + lc4 + 3]};
      *(half4*)&wqkvT[(size_t)(c0 + cl) * 1024 + r0 + lc4] = o;
    }
  }
}

// ---------------- 128x128 BK=64 co-resident GEMM ----------------
// A[M][K] f16 row-major, BT[N][K] f16 row-major. 256 threads = 4 waves (2Mx2N),
// per-wave output 64x64 (acc[4][4]). LDS: 2 dbuf x (A 16KB + B 16KB) = 64KB.
// Tile layout [128 rows][128B], XOR swizzle byte ^= ((row&7)<<4); staged
// linearly via global_load_lds with inverse-swizzled global source column.

// stage one full 128x64-f16 tile region = 4 sweeps x 1 gld16/thread
__device__ __forceinline__ void stage_tile(const _Float16* __restrict__ G, int K,
                                           int rowbase, int kt, char* region,
                                           int t) {
  char* wbase = region + (t & ~63) * 16;  // + lane*16 done by HW
#pragma unroll
  for (int q = 0; q < 4; ++q) {
    const int row = q * 32 + (t >> 3);
    const int col8 = ((t & 7) ^ (row & 7)) * 8;  // inverse-swizzled f16 col
    gld16(G + (size_t)(rowbase + row) * K + kt + col8, wbase + q * 4096);
  }
}

// stage a 64-row tile region = 2 sweeps (for split kv B-tiles)
__device__ __forceinline__ void stage_tile64(const _Float16* __restrict__ G,
                                             int K, int rowbase, int kt,
                                             char* region, int t) {
  char* wbase = region + (t & ~63) * 16;
#pragma unroll
  for (int q = 0; q < 2; ++q) {
    const int row = q * 32 + (t >> 3);
    const int col8 = ((t & 7) ^ (row & 7)) * 8;
    gld16(G + (size_t)(rowbase + row) * K + kt + col8, wbase + q * 4096);
  }
}

// EPI 0: tileN<4 -> fused softmax(q) -> oQ[16384][512];
//        tileN>=4 -> head h=tileN-4, B-cols [k_h | v_h]; epilogue computes
//        64x64 partial ek^T v via MFMA + colsums -> ctxpart(f16)/colpart.
// EPI 1: +bias, f32 out ldc=1024 (A=softq, BT=CW^T per batch via bstride).
template <int EPI>
__global__ __launch_bounds__(256, 2) void gemm128(
    const _Float16* __restrict__ A, const _Float16* __restrict__ BT, int K,
    int NTN, int bstride, _Float16* __restrict__ oQ,
    _Float16* __restrict__ ctxpart, float* __restrict__ colpart,
    float* __restrict__ oC, const float* __restrict__ bias) {
  __shared__ char lds[65536];
  const int t = threadIdx.x;
  const int l = t & 63, w = t >> 6;
  const int wm = w >> 1, wn = w & 1;  // wave -> 64x64 quadrant
  const int fr = l & 15, qq = l >> 4;
  const int swzx = (fr & 7) << 4;

  // T1: bijective XCD chunking (nwg % 8 == 0), tileM-major within chunk
  const int nwg = gridDim.x;
  const int cpx = nwg >> 3;
  const int wg = (blockIdx.x & 7) * cpx + (blockIdx.x >> 3);
  const int tileM = wg / NTN, tileN = wg - tileM * NTN;
  const int mbase = tileM * 128, nbase = tileN * 128;
  BT += (size_t)(tileM >> 6) * bstride;  // per-batch B (0 for GEMM1)

  const int NT = K >> 6;
  f32x4 acc[4][4] = {};
  half8 a[4][2], b[4][2];

  // stage both operands of K-tile `tile` into buffer (tile&1); 8 loads/thread
  auto STG = [&](int tile) {
    int kt = tile * 64;
    if (kt > K - 64) kt = K - 64;  // tail clamp: identical issue counts
    char* base = lds + ((tile & 1) << 15);
    stage_tile(A, K, mbase, kt, base, t);  // 4 loads
    if (EPI == 1 || tileN < 4) {
      stage_tile(BT, K, nbase, kt, base + 16384, t);  // 4 loads
    } else {
      const int h = tileN - 4;
      stage_tile64(BT, K, 512 + h * 64, kt, base + 16384, t);          // k_h
      stage_tile64(BT, K, 1024 + h * 64, kt, base + 16384 + 8192, t);  // v_h
    }
  };

  // prologue: tile0 only; drain + barrier -> tile0 resident block-wide
  STG(0);
  asm volatile("s_waitcnt vmcnt(0)" ::: "memory");
  __builtin_amdgcn_s_barrier();

  for (int t2 = 0; t2 < NT; ++t2) {
    const char* ldsA = lds + ((t2 & 1) << 15);
    const char* ldsB = ldsA + 16384;
    // issue next-tile staging (-> other buf; its previous readers drained at
    // BAR(t2-1)), then this tile's frag reads (cur). reads->MFMA ordering is
    // per-wave register scoreboard; no barrier needed before MFMA1.
    STG(t2 + 1);
#pragma unroll
    for (int mi = 0; mi < 4; ++mi)
#pragma unroll
      for (int kk = 0; kk < 2; ++kk) {
        int off = (wm * 64 + mi * 16 + fr) * 128 + ((kk * 64 + qq * 16) ^ swzx);
        a[mi][kk] = *(const half8*)(ldsA + off);
      }
#pragma unroll
    for (int ni = 0; ni < 4; ++ni)
#pragma unroll
      for (int kk = 0; kk < 2; ++kk) {
        int off = (wn * 64 + ni * 16 + fr) * 128 + ((kk * 64 + qq * 16) ^ swzx);
        b[ni][kk] = *(const half8*)(ldsB + off);
      }
    __builtin_amdgcn_s_setprio(1);
#pragma unroll
    for (int mi = 0; mi < 4; ++mi)
#pragma unroll
      for (int ni = 0; ni < 2; ++ni)
#pragma unroll
        for (int kk = 0; kk < 2; ++kk)
          acc[mi][ni] = __builtin_amdgcn_mfma_f32_16x16x32_f16(
              a[mi][kk], b[ni][kk], acc[mi][ni], 0, 0, 0);
    __builtin_amdgcn_s_setprio(0);
    // single drain+barrier per K-tile: lgkm0 -> all cur reads done (so next
    // iter's STG(t2+2)->cur is race-free); vmcnt0 -> tile t2+1 resident (so
    // next iter's reads of other are valid). "memory" clobber pins ds_reads.
    asm volatile("s_waitcnt vmcnt(0) lgkmcnt(0)" ::: "memory");
    __builtin_amdgcn_s_barrier();
    __builtin_amdgcn_s_setprio(1);
#pragma unroll
    for (int mi = 0; mi < 4; ++mi)
#pragma unroll
      for (int ni = 2; ni < 4; ++ni)
#pragma unroll
        for (int kk = 0; kk < 2; ++kk)
          acc[mi][ni] = __builtin_amdgcn_mfma_f32_16x16x32_f16(
              a[mi][kk], b[ni][kk], acc[mi][ni], 0, 0, 0);
    __builtin_amdgcn_s_setprio(0);
  }
  // all gld16/ds_read drained at final iter's vmcnt0/lgkm0+BAR; MFMA2 after
  // that BAR is register-only. One barrier so all waves left the loop LDS.
  __builtin_amdgcn_s_barrier();

  // C/D layout: col = lane&15 (=fr), row = (lane>>4)*4 + reg (=qq*4+r)
  if (EPI == 0) {
    if (tileN < 4) {
      // fused softmax over head dim (4 in-reg + shfl_xor<16), store softq
      const int gcol0 = nbase + wn * 64;
#pragma unroll
      for (int mi = 0; mi < 4; ++mi) {
        const int grow = mbase + wm * 64 + mi * 16 + qq * 4;
        float e[4][4], rs[4];
#pragma unroll
        for (int r = 0; r < 4; ++r) {
          float s = 0.f;
#pragma unroll
          for (int ni = 0; ni < 4; ++ni) {
            e[ni][r] = __expf(acc[mi][ni][r]);
            s += e[ni][r];
          }
#pragma unroll
          for (int off = 1; off < 16; off <<= 1) s += __shfl_xor(s, off, 64);
          rs[r] = 1.f / s;
        }
#pragma unroll
        for (int ni = 0; ni < 4; ++ni) {
          const int gcol = gcol0 + ni * 16 + fr;
#pragma unroll
          for (int r = 0; r < 4; ++r)
            oQ[(size_t)(grow + r) * 512 + gcol] = (_Float16)(e[ni][r] * rs[r]);
        }
      }
    } else {
      // kv path (MFMA ctx): local cols 0-63 = k logits (wn=0), 64-127 = v.
      const int h = tileN - 4;
      float* credu = (float*)(lds + 32768);  // [2][64] colsum partials
      // exp on k-quadrant + in-register colsum (sum over this wave's 64 n)
      if (wn == 0) {
#pragma unroll
        for (int mi = 0; mi < 4; ++mi)
#pragma unroll
          for (int ni = 0; ni < 4; ++ni) {
            f32x4 e4;
#pragma unroll
            for (int r = 0; r < 4; ++r) e4[r] = __expf(acc[mi][ni][r]);
            acc[mi][ni] = e4;
          }
        float s[4] = {};
#pragma unroll
        for (int ni = 0; ni < 4; ++ni) {
#pragma unroll
          for (int mi = 0; mi < 4; ++mi)
#pragma unroll
            for (int r = 0; r < 4; ++r) s[ni] += acc[mi][ni][r];
          s[ni] += __shfl_xor(s[ni], 16, 64);
          s[ni] += __shfl_xor(s[ni], 32, 64);
        }
        if (l < 16) {
#pragma unroll
          for (int ni = 0; ni < 4; ++ni) credu[wm * 64 + ni * 16 + fr] = s[ni];
        }
      }
      // transposed f16 dump: ekT[64 c][128 n] @lds+0, vT @lds+16384;
      // swizzle: byte ^= ((c&15)<<4) on the n-offset (16B-chunk involution)
      {
        char* dst8 = lds + (wn ? 16384 : 0);
#pragma unroll
        for (int mi = 0; mi < 4; ++mi) {
          const int nb = (wm * 64 + mi * 16 + qq * 4) * 2;  // n byte offset
#pragma unroll
          for (int ni = 0; ni < 4; ++ni) {
            const int c = ni * 16 + fr;
            half4 pk = {(_Float16)acc[mi][ni][0], (_Float16)acc[mi][ni][1],
                        (_Float16)acc[mi][ni][2], (_Float16)acc[mi][ni][3]};
            *(half4*)(dst8 + c * 256 + (nb ^ ((c & 15) << 4))) = pk;
          }
        }
      }
      __syncthreads();
      // MFMA: D[d][e] = sum_n ekT[d][n]*vT[e][n]; wave w -> e in [w*16,+16)
      half8 bf[4];
      const int erow = w * 16 + fr;
#pragma unroll
      for (int kk = 0; kk < 4; ++kk)
        bf[kk] = *(const half8*)(lds + 16384 + erow * 256 +
                                 ((kk * 64 + qq * 16) ^ ((erow & 15) << 4)));
      f32x4 dacc[4] = {};
#pragma unroll
      for (int mi = 0; mi < 4; ++mi) {
        const int drow = mi * 16 + fr;
#pragma unroll
        for (int kk = 0; kk < 4; ++kk) {
          half8 af = *(const half8*)(lds + drow * 256 +
                                     ((kk * 64 + qq * 16) ^ ((drow & 15) << 4)));
          dacc[mi] =
              __builtin_amdgcn_mfma_f32_16x16x32_f16(af, bf[kk], dacc[mi], 0, 0, 0);
        }
      }
      const int bh = (tileM >> 6) * 8 + h, chunk = tileM & 63;
      _Float16* cp = ctxpart + ((size_t)bh * 64 + chunk) * 4096;
#pragma unroll
      for (int mi = 0; mi < 4; ++mi)
#pragma unroll
        for (int r = 0; r < 4; ++r)
          cp[(mi * 16 + qq * 4 + r) * 64 + w * 16 + fr] =
              (_Float16)dacc[mi][r];
      if (t < 16) {
        f32x4 c0 = *(const f32x4*)&credu[t * 4];
        f32x4 c1 = *(const f32x4*)&credu[64 + t * 4];
        *(f32x4*)&colpart[((size_t)bh * 64 + chunk) * 64 + t * 4] = c0 + c1;
      }
    }
  } else {
#pragma unroll
    for (int mi = 0; mi < 4; ++mi) {
      const int grow = mbase + wm * 64 + mi * 16 + qq * 4;
#pragma unroll
      for (int ni = 0; ni < 4; ++ni) {
        const int gcol = nbase + wn * 64 + ni * 16 + fr;
        const float bb = bias[gcol];
#pragma unroll
        for (int r = 0; r < 4; ++r)
          oC[(size_t)(grow + r) * 1024 + gcol] = acc[mi][ni][r] + bb;
      }
    }
  }
}

// Merged reduce + CW^T: block = (bh, d). Reduces 64 chunk-partials (f16),
// divides by colsum, then CW^T[b][o][h*64+d] = sum_e crow[e]*Wout[h*64+e][o].
__global__ __launch_bounds__(256) void ctxw_kernel(
    const _Float16* __restrict__ ctxpart, const float* __restrict__ colpart,
    const float* __restrict__ Wout, _Float16* __restrict__ cwT) {
  __shared__ float part[4][64];
  __shared__ float csp[64];
  __shared__ float crow[64];
  const int blk = blockIdx.x;
  const int bh = blk >> 6, d = blk & 63;
  const int b = bh >> 3, h = bh & 7;
  const int t = threadIdx.x;
  const int e = t & 63, cq = t >> 6;
  float p = 0.f;
#pragma unroll
  for (int cc = 0; cc < 16; ++cc)
    p += (float)ctxpart[((size_t)bh * 64 + cq * 16 + cc) * 4096 + d * 64 + e];
  part[cq][e] = p;
  if (t >= 64 && t < 128)
    csp[t - 64] = colpart[((size_t)bh * 64 + (t - 64)) * 64 + d];
  __syncthreads();
  if (t < 64) {
    float csum = 0.f;
#pragma unroll
    for (int c = 0; c < 64; ++c) csum += csp[c];
    crow[t] = (part[0][t] + part[1][t] + part[2][t] + part[3][t]) / csum;
  }
  __syncthreads();
  float acc[4] = {};
  for (int e2 = 0; e2 < 64; ++e2) {
    const float c = crow[e2];
    const float* wr = Wout + (size_t)(h * 64 + e2) * 1024 + t;
#pragma unroll
    for (int j = 0; j < 4; ++j) acc[j] += c * wr[j * 256];
  }
  _Float16* dst = cwT + (size_t)b * 524288 + (size_t)t * 512 + h * 64 + d;
#pragma unroll
  for (int j = 0; j < 4; ++j) dst[(size_t)j * 256 * 512] = (_Float16)acc[j];
}

extern "C" void kernel_launch(void* const* d_in, const int* in_sizes, int n_in,
                              void* d_out, int out_size, void* d_ws, size_t ws_size,
                              hipStream_t stream) {
  const float* x = (const float*)d_in[0];
  const float* Wqkv = (const float*)d_in[1];
  const float* Wout = (const float*)d_in[2];
  const float* bout = (const float*)d_in[3];
  float* out = (float*)d_out;
  char* ws = (char*)d_ws;

  _Float16* xb = (_Float16*)(ws + WS_XB);
  _Float16* wqkvT = (_Float16*)(ws + WS_WQKVT);
  _Float16* cwT = (_Float16*)(ws + WS_CWT);
  _Float16* sq = (_Float16*)(ws + WS_SQ);
  _Float16* ctxpart = (_Float16*)(ws + WS_CTXPART);
  float* colpart = (float*)(ws + WS_COLPART);

  // 1) fused converts (x cvt + LDS-tiled W_qkv transpose)
  prep_kernel<<<16768, 256, 0, stream>>>(x, Wqkv, xb, wqkvT);
  // 2) qkv projection; q blocks -> fused softmax -> sq; kv blocks -> fused
  //    MFMA partial-context -> ctxpart(f16)/colpart
  gemm128<0><<<1536, 256, 0, stream>>>(xb, wqkvT, 1024, 12, 0, sq, ctxpart,
                                       colpart, nullptr, nullptr);
  // 3) reduce + CW^T = (ctx @ W_out)^T per batch
  ctxw_kernel<<<1024, 256, 0, stream>>>(ctxpart, colpart, Wout, cwT);
  // 4) out = softq @ CW + b  (M=16384,N=1024,K=512; B selected per batch)
  gemm128<1><<<1024, 256, 0, stream>>>(sq, cwT, 512, 8, 524288, nullptr,
                                       nullptr, nullptr, out, bout);
}